// Round 11
// baseline (967.838 us; speedup 1.0000x reference)
//
#include <hip/hip_runtime.h>
#include <math.h>

// ============================================================================
// MAEEG classification, round 11:
//   - conv chain bf16 end-to-end: convmm writes bf16; GN reads bf16 (u32-pair
//     vectorized), fp32 stats/GELU, writes padded bf16 shadow (GN0/GN1) or
//     fp32 for transpose (GN2). Kills ~112MB of dead fp32 conv outputs.
//   - fattn v2: K/V staged via global_load_lds (source-swizzled, 1KB/wave
//     issue), double-buffered prefetch (stage kt+1 before compute kt),
//     quad-transpose P writes (2x shfl_xor rounds -> 1 ds_write_b64 per idx
//     instead of 4 ds_write_b16). Math identical to v1.
//   - mm / mmln / convmm core / cls unchanged from round 10.
// ============================================================================

typedef unsigned int   u32;
typedef unsigned short u16;
typedef __attribute__((ext_vector_type(4))) float f32x4;
typedef __attribute__((ext_vector_type(8))) short bf16x8;

__device__ __forceinline__ u16 f2bf(float v) {
    union { float f; u32 u; } x; x.f = v;
    u32 r = x.u + 0x7fffu + ((x.u >> 16) & 1u);  // RNE
    return (u16)(r >> 16);
}

// async global->LDS DMA, 16B per lane; ldst must be wave-uniform
__device__ __forceinline__ void gl2lds16(const void* gsrc, void* ldst) {
    __builtin_amdgcn_global_load_lds(
        (const __attribute__((address_space(1))) void*)gsrc,
        (__attribute__((address_space(3))) void*)ldst, 16, 0, 0);
}

// ---------------------------------------------------------------------------
__device__ __forceinline__ float maeeg_block_sum(float v, float* sc4) {
#pragma unroll
    for (int off = 32; off; off >>= 1) v += __shfl_down(v, off);
    int t = threadIdx.x;
    if ((t & 63) == 0) sc4[t >> 6] = v;
    __syncthreads();
    float r = sc4[0] + sc4[1] + sc4[2] + sc4[3];
    __syncthreads();
    return r;
}

// ---------------------------------------------------------------------------
// bf16 MFMA GEMM: out[m][n] = sum_k A[m][k]*B[n][k] (+bias[n]) (+res)
// flags: 1 relu | 2 bf16 out | 4 transposed bf16 out | 16 fused-QKV routing
__global__ __launch_bounds__(256) void maeeg_mm_kernel(
    const u16* __restrict__ Ag, const u16* __restrict__ Bg,
    const float* __restrict__ bias, const float* __restrict__ res,
    void* __restrict__ outp, int N, int K, int flags)
{
    __shared__ u16 As[8192];  // [128 rows][64 k] bf16, 128B/row, XOR-swizzled
    __shared__ u16 Bs[8192];
    const int m0 = blockIdx.x * 128, n0 = blockIdx.y * 128;
    const int t = threadIdx.x, w = t >> 6, lane = t & 63;
    const int fr = lane & 15, fq = lane >> 4;
    const int wm = (w >> 1) * 64, wn = (w & 1) * 64;
    const int srow = lane >> 3;
    const int srcc = (lane & 7) ^ srow;

    f32x4 acc[4][4];
    const f32x4 zero = {0.f, 0.f, 0.f, 0.f};
#pragma unroll
    for (int i = 0; i < 4; ++i)
#pragma unroll
        for (int j = 0; j < 4; ++j) acc[i][j] = zero;

    for (int k0 = 0; k0 < K; k0 += 64) {
#pragma unroll
        for (int j = 0; j < 4; ++j) {
            int rowb = w * 32 + j * 8;
            int r = rowb + srow;
            gl2lds16(Ag + (size_t)(m0 + r) * K + k0 + srcc * 8,
                     (char*)As + rowb * 128);
            gl2lds16(Bg + (size_t)(n0 + r) * K + k0 + srcc * 8,
                     (char*)Bs + rowb * 128);
        }
        __syncthreads();
#pragma unroll
        for (int kc = 0; kc < 2; ++kc) {
            bf16x8 af[4], bfv[4];
#pragma unroll
            for (int i = 0; i < 4; ++i) {
                int am = wm + i * 16 + fr;
                int bn = wn + i * 16 + fr;
                int kb = kc * 64 + fq * 16;
                af[i]  = *(const bf16x8*)((const char*)As + am * 128 + (kb ^ ((am & 7) << 4)));
                bfv[i] = *(const bf16x8*)((const char*)Bs + bn * 128 + (kb ^ ((bn & 7) << 4)));
            }
#pragma unroll
            for (int i = 0; i < 4; ++i)
#pragma unroll
                for (int j = 0; j < 4; ++j)
                    acc[i][j] = __builtin_amdgcn_mfma_f32_16x16x32_bf16(
                        af[i], bfv[j], acc[i][j], 0, 0, 0);
        }
        __syncthreads();
    }
#pragma unroll
    for (int i = 0; i < 4; ++i) {
#pragma unroll
        for (int j = 0; j < 4; ++j) {
            int n = n0 + wn + j * 16 + fr;
            float bv = bias ? bias[n] : 0.f;
#pragma unroll
            for (int r = 0; r < 4; ++r) {
                int m = m0 + wm + i * 16 + fq * 4 + r;
                float v = acc[i][j][r] + bv;
                if (res) v += res[(size_t)m * N + n];
                if (flags & 1) v = fmaxf(v, 0.f);
                if (flags & 16) {
                    // fused QKV: seg0 -> Q (scaled), seg1 -> K, seg2 -> V^T
                    u16* o = (u16*)outp;
                    int seg = n >> 8, nn = n & 255;
                    if (seg == 0)
                        o[(size_t)m * 256 + nn] = f2bf(v * 0.17677669529663687f);
                    else if (seg == 1)
                        o[4194304 + (size_t)m * 256 + nn] = f2bf(v);
                    else
                        o[8388608 + (((size_t)(m >> 9)) * 256 + nn) * 512 + (m & 511)] = f2bf(v);
                } else if (flags & 4)
                    ((u16*)outp)[(((size_t)(m >> 9)) * 256 + n) * 512 + (m & 511)] = f2bf(v);
                else if (flags & 2)
                    ((u16*)outp)[(size_t)m * N + n] = f2bf(v);
                else
                    ((float*)outp)[(size_t)m * N + n] = v;
            }
        }
    }
}

// ---------------------------------------------------------------------------
// fused GEMM + residual + LayerNorm: out = LN(A@B^T + bias + res)*g + b
__global__ __launch_bounds__(512) void maeeg_mmln_kernel(
    const u16* __restrict__ Ag, const u16* __restrict__ Bg,
    const float* __restrict__ bias, const float* __restrict__ res,
    const float* __restrict__ g, const float* __restrict__ b,
    float* __restrict__ outf, u16* __restrict__ outb, int K)
{
    __shared__ u16 As[64 * 64];    // 8KB  [64 m][64 k], swizzled
    __shared__ u16 Bs[256 * 64];   // 32KB [256 n][64 k]
    __shared__ float psum[64][4];
    __shared__ float psq[64][4];
    const int m0 = blockIdx.x * 64;
    const int t = threadIdx.x, w = t >> 6, lane = t & 63;
    const int fr = lane & 15, fq = lane >> 4;
    const int wm = (w & 1) * 32, wn = (w >> 1) * 64;
    const int seg = w >> 1;
    const int srow = lane >> 3;
    const int srcc = (lane & 7) ^ srow;

    f32x4 acc[2][4];
    const f32x4 zero = {0.f, 0.f, 0.f, 0.f};
#pragma unroll
    for (int i = 0; i < 2; ++i)
#pragma unroll
        for (int j = 0; j < 4; ++j) acc[i][j] = zero;

    for (int k0 = 0; k0 < K; k0 += 64) {
        gl2lds16(Ag + (size_t)(m0 + w * 8 + srow) * K + k0 + srcc * 8,
                 (char*)As + (w * 8) * 128);
#pragma unroll
        for (int j = 0; j < 4; ++j) {
            int rowb = w * 32 + j * 8;
            gl2lds16(Bg + (size_t)(rowb + srow) * K + k0 + srcc * 8,
                     (char*)Bs + rowb * 128);
        }
        __syncthreads();
#pragma unroll
        for (int kc = 0; kc < 2; ++kc) {
            int kb = kc * 64 + fq * 16;
            bf16x8 af[2], bfv[4];
#pragma unroll
            for (int i = 0; i < 2; ++i) {
                int am = wm + i * 16 + fr;
                af[i] = *(const bf16x8*)((const char*)As + am * 128 + (kb ^ ((am & 7) << 4)));
            }
#pragma unroll
            for (int j = 0; j < 4; ++j) {
                int bn = wn + j * 16 + fr;
                bfv[j] = *(const bf16x8*)((const char*)Bs + bn * 128 + (kb ^ ((bn & 7) << 4)));
            }
#pragma unroll
            for (int i = 0; i < 2; ++i)
#pragma unroll
                for (int j = 0; j < 4; ++j)
                    acc[i][j] = __builtin_amdgcn_mfma_f32_16x16x32_bf16(
                        af[i], bfv[j], acc[i][j], 0, 0, 0);
        }
        __syncthreads();
    }

#pragma unroll
    for (int j = 0; j < 4; ++j) {
        int n = wn + j * 16 + fr;
        float bv = bias ? bias[n] : 0.f;
#pragma unroll
        for (int i = 0; i < 2; ++i)
#pragma unroll
            for (int r = 0; r < 4; ++r) {
                int m = m0 + wm + i * 16 + fq * 4 + r;
                acc[i][j][r] += bv + res[(size_t)m * 256 + n];
            }
    }
#pragma unroll
    for (int i = 0; i < 2; ++i)
#pragma unroll
        for (int r = 0; r < 4; ++r) {
            float s = acc[i][0][r] + acc[i][1][r] + acc[i][2][r] + acc[i][3][r];
            float q = acc[i][0][r] * acc[i][0][r] + acc[i][1][r] * acc[i][1][r]
                    + acc[i][2][r] * acc[i][2][r] + acc[i][3][r] * acc[i][3][r];
#pragma unroll
            for (int off = 1; off < 16; off <<= 1) {
                s += __shfl_xor(s, off);
                q += __shfl_xor(q, off);
            }
            if (fr == 0) {
                int ml = wm + i * 16 + fq * 4 + r;
                psum[ml][seg] = s;
                psq[ml][seg] = q;
            }
        }
    __syncthreads();
#pragma unroll
    for (int i = 0; i < 2; ++i)
#pragma unroll
        for (int r = 0; r < 4; ++r) {
            int ml = wm + i * 16 + fq * 4 + r;
            float S = psum[ml][0] + psum[ml][1] + psum[ml][2] + psum[ml][3];
            float Q = psq[ml][0] + psq[ml][1] + psq[ml][2] + psq[ml][3];
            float mu = S * (1.f / 256.f);
            float var = fmaxf(Q * (1.f / 256.f) - mu * mu, 0.f);
            float rs = rsqrtf(var + 1e-5f);
            size_t mrow = (size_t)(m0 + ml) * 256;
#pragma unroll
            for (int j = 0; j < 4; ++j) {
                int n = wn + j * 16 + fr;
                float o = (acc[i][j][r] - mu) * rs * g[n] + b[n];
                if (outf) outf[mrow + n] = o;
                outb[mrow + n] = f2bf(o);
            }
        }
}

// ---------------------------------------------------------------------------
// bf16 MFMA implicit-GEMM conv1d (stride 2, taps 15 padded to 16). bf16 out.
__global__ __launch_bounds__(256) void maeeg_convmm_kernel(
    const u16* __restrict__ Wp, const u16* __restrict__ inp,
    const float* __restrict__ cb, u16* __restrict__ out,
    int K3, int len_in, int len_out)
{
    __shared__ u16 As[8192];
    __shared__ u16 Bs[8192];
    const int m0 = blockIdx.x * 128, t0 = blockIdx.y * 128, b = blockIdx.z;
    const int lip = len_in + 16;
    const u16* inb = inp + (size_t)b * (K3 >> 4) * lip;
    const int t = threadIdx.x, w = t >> 6, lane = t & 63;
    const int sr = lane & 7, sc = lane >> 3;
    const int fr = lane & 15, fq = lane >> 4;
    const int wm = (w >> 1) * 64, wn = (w & 1) * 64;
    const int srow = lane >> 3;
    const int srcc = (lane & 7) ^ srow;

    f32x4 acc[4][4];
    const f32x4 zero = {0.f, 0.f, 0.f, 0.f};
#pragma unroll
    for (int i = 0; i < 4; ++i)
#pragma unroll
        for (int j = 0; j < 4; ++j) acc[i][j] = zero;

    for (int k0 = 0; k0 < K3; k0 += 64) {
#pragma unroll
        for (int j = 0; j < 4; ++j) {
            int rowb = w * 32 + j * 8;
            gl2lds16(Wp + (size_t)(m0 + rowb + srow) * K3 + k0 + srcc * 8,
                     (char*)As + rowb * 128);
            int row = rowb + sr;
            int k  = k0 + sc * 8;
            int ci = k >> 4, rr = k & 15;
            int tg = t0 + row;
            const u16* gp = inb + (size_t)ci * lip + 2 * tg + rr;
            uint4 vb;
            vb.x = *(const u32*)(gp);
            vb.y = *(const u32*)(gp + 2);
            vb.z = *(const u32*)(gp + 4);
            vb.w = *(const u32*)(gp + 6);
            int kb = (sc ^ (row & 7)) << 4;
            *(uint4*)((char*)Bs + row * 128 + kb) = vb;
        }
        __syncthreads();
#pragma unroll
        for (int kc = 0; kc < 2; ++kc) {
            bf16x8 af[4], bfv[4];
#pragma unroll
            for (int i = 0; i < 4; ++i) {
                int am = wm + i * 16 + fr;
                int bn = wn + i * 16 + fr;
                int kb = kc * 64 + fq * 16;
                af[i]  = *(const bf16x8*)((const char*)As + am * 128 + (kb ^ ((am & 7) << 4)));
                bfv[i] = *(const bf16x8*)((const char*)Bs + bn * 128 + (kb ^ ((bn & 7) << 4)));
            }
#pragma unroll
            for (int i = 0; i < 4; ++i)
#pragma unroll
                for (int j = 0; j < 4; ++j)
                    acc[i][j] = __builtin_amdgcn_mfma_f32_16x16x32_bf16(
                        af[i], bfv[j], acc[i][j], 0, 0, 0);
        }
        __syncthreads();
    }
#pragma unroll
    for (int i = 0; i < 4; ++i) {
#pragma unroll
        for (int r = 0; r < 4; ++r) {
            int m = m0 + wm + i * 16 + fq * 4 + r;
            float bb = cb[m];
            u16* op = out + ((size_t)b * 256 + m) * len_out + t0;
#pragma unroll
            for (int j = 0; j < 4; ++j)
                op[wn + j * 16 + fr] = f2bf(acc[i][j][r] + bb);
        }
    }
}

// ---------------------------------------------------------------------------
// MFMA flash attention v2: gl2lds double-buffered K/V staging + quad-transpose
// P writes. Math identical to v1. grid (4,8,32), 256 thr (4 waves x 32 rows).
__global__ __launch_bounds__(256) void maeeg_fattn_kernel(
    const u16* __restrict__ Qb, const u16* __restrict__ Kb,
    const u16* __restrict__ Vt, u16* __restrict__ att)
{
    __shared__ u16 Ks[2][64 * 32];   // [64 kk][32 d], 64B rows, chunk^=(kk&3)
    __shared__ u16 Vs[2][32 * 64];   // [32 d][64 kk], 128B rows, chunk^=(d&7)
    __shared__ u16 Ps[4][32 * 64];   // per-wave [32 q][64 kk], chunk^=(q&7)
    const int qt = blockIdx.x, h = blockIdx.y, b = blockIdx.z;
    const int t = threadIdx.x, w = t >> 6, lane = t & 63;
    const int fr = lane & 15, fq = lane >> 4;
    const u16* qbase = Qb + (size_t)b * 512 * 256 + h * 32;
    const u16* kbase = Kb + (size_t)b * 512 * 256 + h * 32;
    const u16* vbase = Vt + (size_t)b * 256 * 512 + (size_t)h * 32 * 512;

    // staging maps: wave w stages K rows w*16..+15 and V d-rows w*8..+7 (1KB each)
    const int krow = w * 16 + (lane >> 2);
    const int kcc  = (lane & 3) ^ (krow & 3);
    const int vd   = w * 8 + (lane >> 3);
    const int vcc  = (lane & 7) ^ (vd & 7);

    bf16x8 qf[2];
#pragma unroll
    for (int mi = 0; mi < 2; ++mi)
        qf[mi] = *(const bf16x8*)(qbase +
                 (size_t)(qt * 128 + w * 32 + mi * 16 + fr) * 256 + fq * 8);

    f32x4 oacc[2][2];
    const f32x4 zero = {0.f, 0.f, 0.f, 0.f};
    oacc[0][0] = zero; oacc[0][1] = zero; oacc[1][0] = zero; oacc[1][1] = zero;
    float mrun[8], lrun[8];
#pragma unroll
    for (int i = 0; i < 8; ++i) { mrun[i] = -1e30f; lrun[i] = 0.f; }

    // prologue: stage tile 0 into buf 0
    gl2lds16(kbase + (size_t)krow * 256 + kcc * 8, (char*)Ks[0] + w * 1024);
    gl2lds16(vbase + (size_t)vd * 512 + vcc * 8, (char*)Vs[0] + w * 1024);
    __syncthreads();  // compiler drains vmcnt before barrier

    int buf = 0;
    for (int ti = 0; ti < 8; ++ti) {
        if (ti < 7) {  // prefetch next tile into the other buffer
            int ktn = (ti + 1) * 64;
            gl2lds16(kbase + (size_t)(ktn + krow) * 256 + kcc * 8,
                     (char*)Ks[buf ^ 1] + w * 1024);
            gl2lds16(vbase + (size_t)vd * 512 + ktn + vcc * 8,
                     (char*)Vs[buf ^ 1] + w * 1024);
        }

        // ---- QK^T: S[32 q][64 kk] ----
        f32x4 sacc[2][4];
#pragma unroll
        for (int mi = 0; mi < 2; ++mi)
#pragma unroll
            for (int ni = 0; ni < 4; ++ni) sacc[mi][ni] = zero;
        bf16x8 kf[4];
#pragma unroll
        for (int ni = 0; ni < 4; ++ni) {
            int kk = ni * 16 + fr;
            kf[ni] = *(const bf16x8*)((const char*)Ks[buf] + kk * 64 +
                                      ((fq ^ (kk & 3)) << 4));
        }
        bf16x8 vf[2][2];
#pragma unroll
        for (int nj = 0; nj < 2; ++nj)
#pragma unroll
            for (int kc = 0; kc < 2; ++kc) {
                int d = nj * 16 + fr;
                int ch = (kc * 4 + fq) ^ (d & 7);
                vf[nj][kc] = *(const bf16x8*)((const char*)Vs[buf] + d * 128 + (ch << 4));
            }
#pragma unroll
        for (int mi = 0; mi < 2; ++mi)
#pragma unroll
            for (int ni = 0; ni < 4; ++ni)
                sacc[mi][ni] = __builtin_amdgcn_mfma_f32_16x16x32_bf16(
                    qf[mi], kf[ni], sacc[mi][ni], 0, 0, 0);

        // ---- online softmax; P -> LDS via 4x4 quad transpose (b64 writes) ----
#pragma unroll
        for (int mi = 0; mi < 2; ++mi) {
#pragma unroll
            for (int reg = 0; reg < 4; ++reg) {
                int idx = mi * 4 + reg;
                float rm = fmaxf(fmaxf(sacc[mi][0][reg], sacc[mi][1][reg]),
                                 fmaxf(sacc[mi][2][reg], sacc[mi][3][reg]));
                rm = fmaxf(rm, __shfl_xor(rm, 1));
                rm = fmaxf(rm, __shfl_xor(rm, 2));
                rm = fmaxf(rm, __shfl_xor(rm, 4));
                rm = fmaxf(rm, __shfl_xor(rm, 8));
                float mold = mrun[idx];
                float mnew = fmaxf(mold, rm);
                float c = __expf(mold - mnew);
                mrun[idx] = mnew;
                int q = mi * 16 + fq * 4 + reg;
                float pv[4];
                float psum = 0.f;
#pragma unroll
                for (int ni = 0; ni < 4; ++ni) {
                    pv[ni] = __expf(sacc[mi][ni][reg] - mnew);
                    psum += pv[ni];
                }
                // 4x4 transpose within fr-quads: after this, lane holds the
                // quad's 4 values of ni-block (fr&3): cols (fr&3)*16+(fr&12)+c
                float tq[4], uq[4], wq[4];
#pragma unroll
                for (int i = 0; i < 4; ++i) tq[i] = __shfl_xor(pv[i ^ 1], 1);
#pragma unroll
                for (int i = 0; i < 4; ++i) uq[i] = ((fr ^ i) & 1) ? tq[i] : pv[i];
#pragma unroll
                for (int i = 0; i < 4; ++i) tq[i] = __shfl_xor(uq[i ^ 2], 2);
#pragma unroll
                for (int i = 0; i < 4; ++i) wq[i] = ((fr ^ i) & 2) ? tq[i] : uq[i];
                int col0 = (fr & 3) * 16 + (fr & 12);
                int boff = q * 128 + ((((col0 >> 3) ^ (q & 7)) << 4) | ((col0 & 7) << 1));
                uint2 pk;
                pk.x = (u32)f2bf(wq[0]) | ((u32)f2bf(wq[1]) << 16);
                pk.y = (u32)f2bf(wq[2]) | ((u32)f2bf(wq[3]) << 16);
                *(uint2*)((char*)Ps[w] + boff) = pk;
                lrun[idx] = lrun[idx] * c + psum;
                oacc[mi][0][reg] *= c;
                oacc[mi][1][reg] *= c;
            }
        }

        // ---- PV: O[32 q][32 d] += P @ V ----
        bf16x8 pf[2][2];
#pragma unroll
        for (int mi = 0; mi < 2; ++mi)
#pragma unroll
            for (int kc = 0; kc < 2; ++kc) {
                int q = mi * 16 + fr;
                int ch = (kc * 4 + fq) ^ (q & 7);
                pf[mi][kc] = *(const bf16x8*)((const char*)Ps[w] + q * 128 + (ch << 4));
            }
#pragma unroll
        for (int mi = 0; mi < 2; ++mi)
#pragma unroll
            for (int nj = 0; nj < 2; ++nj) {
                oacc[mi][nj] = __builtin_amdgcn_mfma_f32_16x16x32_bf16(
                    pf[mi][0], vf[nj][0], oacc[mi][nj], 0, 0, 0);
                oacc[mi][nj] = __builtin_amdgcn_mfma_f32_16x16x32_bf16(
                    pf[mi][1], vf[nj][1], oacc[mi][nj], 0, 0, 0);
            }
        __syncthreads();  // drains prefetch vmcnt + protects buffer reuse
        buf ^= 1;
    }

#pragma unroll
    for (int idx = 0; idx < 8; ++idx) {
        float l = lrun[idx];
        l += __shfl_xor(l, 1);
        l += __shfl_xor(l, 2);
        l += __shfl_xor(l, 4);
        l += __shfl_xor(l, 8);
        lrun[idx] = 1.f / l;
    }
    u16* ob = att + (size_t)b * 512 * 256 + h * 32;
#pragma unroll
    for (int mi = 0; mi < 2; ++mi)
#pragma unroll
        for (int reg = 0; reg < 4; ++reg) {
            int q = qt * 128 + w * 32 + mi * 16 + fq * 4 + reg;
            float inv = lrun[mi * 4 + reg];
#pragma unroll
            for (int nj = 0; nj < 2; ++nj)
                ob[(size_t)q * 256 + nj * 16 + fr] =
                    f2bf(oacc[mi][nj][reg] * inv);
        }
}

// ---------------------------------------------------------------------------
// weight prep: one thread per 16-elem output row (15 taps + zero pad)
__global__ void maeeg_prep_convw_kernel(const float* __restrict__ src,
                                        u16* __restrict__ dst, int nrows)
{
    int i = blockIdx.x * 256 + threadIdx.x;
    if (i >= nrows) return;
    const float* s = src + (size_t)i * 15;
    float4 a = *(const float4*)s;
    float4 b = *(const float4*)(s + 4);
    float4 c = *(const float4*)(s + 8);
    float e12 = s[12], e13 = s[13], e14 = s[14];
    uint4 p0, p1;
    p0.x = (u32)f2bf(a.x) | ((u32)f2bf(a.y) << 16);
    p0.y = (u32)f2bf(a.z) | ((u32)f2bf(a.w) << 16);
    p0.z = (u32)f2bf(b.x) | ((u32)f2bf(b.y) << 16);
    p0.w = (u32)f2bf(b.z) | ((u32)f2bf(b.w) << 16);
    p1.x = (u32)f2bf(c.x) | ((u32)f2bf(c.y) << 16);
    p1.y = (u32)f2bf(c.z) | ((u32)f2bf(c.w) << 16);
    p1.z = (u32)f2bf(e12) | ((u32)f2bf(e13) << 16);
    p1.w = (u32)f2bf(e14);
    uint4* d = (uint4*)(dst + (size_t)i * 16);
    d[0] = p0; d[1] = p1;
}

__device__ __forceinline__ uint4 pack8(const float* s) {
    float4 a = ((const float4*)s)[0];
    float4 b = ((const float4*)s)[1];
    uint4 p;
    p.x = (u32)f2bf(a.x) | ((u32)f2bf(a.y) << 16);
    p.y = (u32)f2bf(a.z) | ((u32)f2bf(a.w) << 16);
    p.z = (u32)f2bf(b.x) | ((u32)f2bf(b.y) << 16);
    p.w = (u32)f2bf(b.z) | ((u32)f2bf(b.w) << 16);
    return p;
}

// merged cast for Wo (32768 x8) + Wf1 (131072 x8) + Wf2 (131072 x8)
__global__ void maeeg_cast_www_kernel(
    const float* __restrict__ Wo, u16* __restrict__ dWo,
    const float* __restrict__ Wf1, u16* __restrict__ dWf1,
    const float* __restrict__ Wf2, u16* __restrict__ dWf2)
{
    int i = blockIdx.x * 256 + threadIdx.x;
    const float* s; u16* d; int off;
    if (i < 32768)       { s = Wo;  d = dWo;  off = i; }
    else if (i < 163840) { s = Wf1; d = dWf1; off = i - 32768; }
    else                 { s = Wf2; d = dWf2; off = i - 163840; }
    *(uint4*)(d + (size_t)off * 8) = pack8(s + (size_t)off * 8);
}

// merged QKV pack: [L][65536] x3 -> WQKV [L][3][65536], grid (128, 3)
__global__ void maeeg_cast_qkv3_kernel(
    const float* __restrict__ Wq, const float* __restrict__ Wk,
    const float* __restrict__ Wv, u16* __restrict__ dst)
{
    int seg = blockIdx.y;
    const float* src = (seg == 0) ? Wq : ((seg == 1) ? Wk : Wv);
    int i = blockIdx.x * 256 + threadIdx.x;  // 0..32767
    int l = i >> 13, r = (i & 8191) * 8;
    *(uint4*)(dst + (size_t)l * 196608 + seg * 65536 + r) =
        pack8(src + (size_t)i * 8);
}

// fp32 [rows][len] -> bf16 [rows][len+16], 7 leading zeros; 8 outs/thread
__global__ void maeeg_cast_pad_kernel(const float* __restrict__ src,
                                      u16* __restrict__ dst, int len)
{
    int lip = len + 16;
    int n8 = lip >> 3;
    int i = blockIdx.x * 256 + threadIdx.x;
    if (i >= n8) return;
    int row = blockIdx.y;
    int p0 = i * 8;
    u16 vals[8];
#pragma unroll
    for (int e = 0; e < 8; ++e) {
        int q = p0 + e - 7;
        vals[e] = (q >= 0 && q < len) ? f2bf(src[(size_t)row * len + q]) : (u16)0;
    }
    uint4 pk;
    pk.x = (u32)vals[0] | ((u32)vals[1] << 16);
    pk.y = (u32)vals[2] | ((u32)vals[3] << 16);
    pk.z = (u32)vals[4] | ((u32)vals[5] << 16);
    pk.w = (u32)vals[6] | ((u32)vals[7] << 16);
    *(uint4*)(dst + (size_t)row * lip + p0) = pk;
}

// sinusoidal PE table [512][256]
__global__ void maeeg_pe_kernel(float* __restrict__ pet)
{
    int s = blockIdx.x, e = threadIdx.x;
    float ang = (float)s / powf(10000.f, (float)e * (1.f / 256.f));
    pet[s * 256 + e] = (e & 1) ? cosf(ang) : sinf(ang);
}

// ---------------------------------------------------------------------------
// GroupNorm (2 ch/group) + exact GELU over bf16 input. Writes padded bf16
// shadow (bfout, nullable) and/or fp32 (f32out, nullable).
__global__ __launch_bounds__(256) void maeeg_gn_gelu_kernel(
    const u16* __restrict__ hin, const float* __restrict__ g,
    const float* __restrict__ bta, int len, u16* __restrict__ bfout, int lip,
    float* __restrict__ f32out)
{
    const int grp = blockIdx.x, b = blockIdx.y;
    const size_t base = ((size_t)b * 256 + grp * 2) * len;
    const u32* p32 = (const u32*)(hin + base);
    float s1 = 0.f, s2 = 0.f;
    for (int i = threadIdx.x; i < len; i += 256) {  // len u32s = 2*len bf16
        u32 v = p32[i];
        union { u32 u; float f; } lo, hi;
        lo.u = v << 16; hi.u = v & 0xffff0000u;
        s1 += lo.f + hi.f;
        s2 += lo.f * lo.f + hi.f * hi.f;
    }
    __shared__ float sc[4];
    float S1 = maeeg_block_sum(s1, sc);
    float S2 = maeeg_block_sum(s2, sc);
    const float nn = (float)(2 * len);
    float mu = S1 / nn;
    float var = fmaxf(S2 / nn - mu * mu, 0.f);
    float rs = rsqrtf(var + 1e-5f);
    float g0 = g[grp * 2], g1 = g[grp * 2 + 1];
    float b0 = bta[grp * 2], b1 = bta[grp * 2 + 1];
    u16* bp = bfout ? bfout + ((size_t)b * 256 + grp * 2) * lip : (u16*)0;
    float* fp = f32out ? f32out + base : (float*)0;
    for (int i2 = threadIdx.x; i2 < len; i2 += 256) {
        u32 v = p32[i2];
        int i = i2 * 2;                  // u16 index of the pair (same channel)
        union { u32 u; float f; } lo, hi;
        lo.u = v << 16; hi.u = v & 0xffff0000u;
        bool c1 = (i >= len);
        float gg = c1 ? g1 : g0, bb = c1 ? b1 : b0;
        float y0 = (lo.f - mu) * rs * gg + bb;
        float y1 = (hi.f - mu) * rs * gg + bb;
        float e0 = 0.5f * y0 * (1.f + erff(y0 * 0.70710678118654752f));
        float e1 = 0.5f * y1 * (1.f + erff(y1 * 0.70710678118654752f));
        if (bp) {
            int j0 = (i < len ? i : i - len + lip) + 7;
            bp[j0] = f2bf(e0);
            bp[j0 + 1] = f2bf(e1);
        }
        if (fp) {
            fp[i] = e0;
            fp[i + 1] = e1;
        }
    }
    if (bp && threadIdx.x < 32) {  // zero the pads (ws is 0xAA-poisoned)
        int ch = threadIdx.x >> 4, pp = threadIdx.x & 15;
        bp[(size_t)ch * lip + ((pp < 7) ? pp : (len + pp))] = 0;
    }
}

// ---------------------------------------------------------------------------
// transpose [B,256,512] -> [B,512,256], add PE from table; fp32 + bf16.
__global__ __launch_bounds__(256) void maeeg_transpose_pos_kernel(
    const float* __restrict__ in, const float* __restrict__ pet,
    float* __restrict__ out, u16* __restrict__ outb)
{
    __shared__ float tile[256][33];
    const int s0 = blockIdx.x * 32, b = blockIdx.y;
    for (int idx = threadIdx.x; idx < 256 * 32; idx += 256) {
        int e = idx >> 5, j = idx & 31;
        tile[e][j] = in[((size_t)b * 256 + e) * 512 + s0 + j];
    }
    __syncthreads();
    for (int idx = threadIdx.x; idx < 32 * 256; idx += 256) {
        int j = idx >> 8, e = idx & 255;
        float v = tile[e][j] + pet[(s0 + j) * 256 + e];
        size_t o = ((size_t)b * 512 + s0 + j) * 256 + e;
        out[o] = v;
        outb[o] = f2bf(v);
    }
}

// ---------------------------------------------------------------------------
// classifier stage 1: MFMA split-K; A via global_load_lds, Wc1 fp32->bf16
// inline (reg-staged). grid (128 ks, 4 jt), 256 thr.
__global__ __launch_bounds__(256) void maeeg_cls1_kernel(
    const u16* __restrict__ flatb, const float* __restrict__ Wc1,
    float* __restrict__ part)
{
    __shared__ u16 As[32 * 64];
    __shared__ u16 Bs[64 * 64];
    const int ks = blockIdx.x, jt = blockIdx.y;
    const int t = threadIdx.x, w = t >> 6, lane = t & 63;
    const int fr = lane & 15, fq = lane >> 4;
    const int kbase0 = ks * 1024;
    const int brow = t >> 2, bq = t & 3;
    const int srow = lane >> 3;
    const int srcc = (lane & 7) ^ srow;

    f32x4 acc[2];
    const f32x4 zero = {0.f, 0.f, 0.f, 0.f};
    acc[0] = zero; acc[1] = zero;

    for (int step = 0; step < 16; ++step) {
        int kk = kbase0 + step * 64;
        int rowb = w * 8;
        gl2lds16(flatb + (size_t)(rowb + srow) * 131072 + kk + srcc * 8,
                 (char*)As + rowb * 128);
        const float* wp = Wc1 + (size_t)(jt * 64 + brow) * 131072 + kk + bq * 16;
        float4 f0 = ((const float4*)wp)[0];
        float4 f1 = ((const float4*)wp)[1];
        float4 f2 = ((const float4*)wp)[2];
        float4 f3 = ((const float4*)wp)[3];
        uint4 p0, p1;
        p0.x = (u32)f2bf(f0.x) | ((u32)f2bf(f0.y) << 16);
        p0.y = (u32)f2bf(f0.z) | ((u32)f2bf(f0.w) << 16);
        p0.z = (u32)f2bf(f1.x) | ((u32)f2bf(f1.y) << 16);
        p0.w = (u32)f2bf(f1.z) | ((u32)f2bf(f1.w) << 16);
        p1.x = (u32)f2bf(f2.x) | ((u32)f2bf(f2.y) << 16);
        p1.y = (u32)f2bf(f2.z) | ((u32)f2bf(f2.w) << 16);
        p1.z = (u32)f2bf(f3.x) | ((u32)f2bf(f3.y) << 16);
        p1.w = (u32)f2bf(f3.z) | ((u32)f2bf(f3.w) << 16);
        int c0 = bq * 2, c1 = bq * 2 + 1;
        *(uint4*)((char*)Bs + brow * 128 + ((c0 ^ (brow & 7)) << 4)) = p0;
        *(uint4*)((char*)Bs + brow * 128 + ((c1 ^ (brow & 7)) << 4)) = p1;
        __syncthreads();
#pragma unroll
        for (int kc = 0; kc < 2; ++kc) {
            int kbyte = kc * 64 + fq * 16;
            int bn = w * 16 + fr;
            bf16x8 bfv = *(const bf16x8*)((const char*)Bs + bn * 128 +
                                          (kbyte ^ ((bn & 7) << 4)));
#pragma unroll
            for (int mi = 0; mi < 2; ++mi) {
                int am = mi * 16 + fr;
                bf16x8 af = *(const bf16x8*)((const char*)As + am * 128 +
                                             (kbyte ^ ((am & 7) << 4)));
                acc[mi] = __builtin_amdgcn_mfma_f32_16x16x32_bf16(
                    af, bfv, acc[mi], 0, 0, 0);
            }
        }
        __syncthreads();
    }
#pragma unroll
    for (int mi = 0; mi < 2; ++mi)
#pragma unroll
        for (int r = 0; r < 4; ++r) {
            int m = mi * 16 + fq * 4 + r;
            int j = jt * 64 + w * 16 + fr;
            part[((size_t)ks * 32 + m) * 256 + j] = acc[mi][r];
        }
}

// fused cls2 (reduce+bias+relu) + cls3 (dot + sigmoid)
__global__ __launch_bounds__(256) void maeeg_cls23_kernel(
    const float* __restrict__ part, const float* __restrict__ bc1,
    const float* __restrict__ Wc2, const float* __restrict__ bc2,
    float* __restrict__ out)
{
    const int b = blockIdx.x, j = threadIdx.x;
    float s = bc1[j];
    for (int ks = 0; ks < 128; ++ks) s += part[((size_t)ks * 32 + b) * 256 + j];
    float v = fmaxf(s, 0.f) * Wc2[j];
    __shared__ float sc[4];
    float tot = maeeg_block_sum(v, sc);
    if (j == 0) out[b] = 1.f / (1.f + expf(-(tot + bc2[0])));
}

// ===========================================================================
extern "C" void kernel_launch(void* const* d_in, const int* in_sizes, int n_in,
                              void* d_out, int out_size, void* d_ws, size_t ws_size,
                              hipStream_t stream)
{
    (void)in_sizes; (void)n_in; (void)out_size; (void)ws_size;
    const float* x        = (const float*)d_in[0];
    const float* conv0_w  = (const float*)d_in[1];
    const float* conv0_b  = (const float*)d_in[2];
    const float* conv12_w = (const float*)d_in[3];
    const float* conv12_b = (const float*)d_in[4];
    const float* gn_g     = (const float*)d_in[5];
    const float* gn_b     = (const float*)d_in[6];
    const float* Wq       = (const float*)d_in[7];
    const float* Wk       = (const float*)d_in[8];
    const float* Wv       = (const float*)d_in[9];
    const float* Wo       = (const float*)d_in[10];
    const float* ln1_g    = (const float*)d_in[11];
    const float* ln1_b    = (const float*)d_in[12];
    const float* Wf1      = (const float*)d_in[13];
    const float* bf1      = (const float*)d_in[14];
    const float* Wf2      = (const float*)d_in[15];
    const float* bf2      = (const float*)d_in[16];
    const float* ln2_g    = (const float*)d_in[17];
    const float* ln2_b    = (const float*)d_in[18];
    const float* Wc1      = (const float*)d_in[19];
    const float* bc1      = (const float*)d_in[20];
    const float* Wc2      = (const float*)d_in[21];
    const float* bc2      = (const float*)d_in[22];
    float* out = (float*)d_out;

    // ---- workspace layout (bytes) ----
    char* wsb = (char*)d_ws;
    u16* WB0   = (u16*)(wsb + 0);          //   524,288
    u16* WB12  = (u16*)(wsb + 524288);     // 4,194,304
    u16* WQKVb = (u16*)(wsb + 4718592);    // 1,572,864 [L][3][256][256]
    u16* WOb   = (u16*)(wsb + 6291456);    //   524,288
    u16* WF1b  = (u16*)(wsb + 6815744);    // 2,097,152
    u16* WF2b  = (u16*)(wsb + 8912896);    // 2,097,152 -> 11,010,048
    // R1: XPAD -> GN1B -> D
    u16*   XPAD  = (u16*)(wsb + 11010048);
    u16*   GN1B  = (u16*)(wsb + 11010048);
    float* D     = (float*)(wsb + 11010048);
    // R2 (67,108,864): CONV0B -> CONV1B -> CONV2B/GN2F -> QKV/ATT/Db -> F1b
    u16*   CONV0B = (u16*)(wsb + 28049408);              // 33.5 MB
    u16*   CONV1B = (u16*)(wsb + 28049408);              // 16.8 MB (conv0 dead)
    u16*   CONV2B = (u16*)(wsb + 28049408 + 33554432);   //  8.4 MB
    float* GN2F   = (float*)(wsb + 28049408);            // 16.8 MB (conv1 dead)
    u16*   Qb2   = (u16*)(wsb + 28049408);               // QKV packed base
    u16*   ATTb  = (u16*)(wsb + 28049408 + 25165824);
    u16*   Db    = (u16*)(wsb + 28049408 + 33554432);
    u16*   F1b   = (u16*)(wsb + 28049408);
    // R3: GN0B -> C + Cb
    u16*   GN0B  = (u16*)(wsb + 95158272);
    float* C     = (float*)(wsb + 95158272);
    u16*   Cb    = (u16*)(wsb + 95158272 + 16777216);    // == flat bf16
    // R4
    float* PART  = (float*)(wsb + 128974848);            // 4,194,304
    float* PET   = (float*)(wsb + 133201920);            //   524,288

    // ---- weight prep ----
    maeeg_prep_convw_kernel<<<64, 256, 0, stream>>>(conv0_w, WB0, 16384);
    maeeg_prep_convw_kernel<<<512, 256, 0, stream>>>(conv12_w, WB12, 131072);
    maeeg_cast_qkv3_kernel<<<dim3(128, 3), 256, 0, stream>>>(Wq, Wk, Wv, WQKVb);
    maeeg_cast_www_kernel<<<1152, 256, 0, stream>>>(Wo, WOb, Wf1, WF1b, Wf2, WF2b);
    maeeg_cast_pad_kernel<<<dim3(3, 2048), 256, 0, stream>>>(x, XPAD, 4096);
    maeeg_pe_kernel<<<512, 256, 0, stream>>>(PET);

    // ---- conv encoder (bf16 chain) ----
    maeeg_convmm_kernel<<<dim3(2, 16, 32), 256, 0, stream>>>(
        WB0, XPAD, conv0_b, CONV0B, 1024, 4096, 2048);
    maeeg_gn_gelu_kernel<<<dim3(128, 32), 256, 0, stream>>>(
        CONV0B, gn_g, gn_b, 2048, GN0B, 2064, (float*)0);
    maeeg_convmm_kernel<<<dim3(2, 8, 32), 256, 0, stream>>>(
        WB12, GN0B, conv12_b, CONV1B, 4096, 2048, 1024);
    maeeg_gn_gelu_kernel<<<dim3(128, 32), 256, 0, stream>>>(
        CONV1B, gn_g + 256, gn_b + 256, 1024, GN1B, 1040, (float*)0);
    maeeg_convmm_kernel<<<dim3(2, 4, 32), 256, 0, stream>>>(
        WB12 + 256 * 4096, GN1B, conv12_b + 256, CONV2B, 4096, 1024, 512);
    maeeg_gn_gelu_kernel<<<dim3(128, 32), 256, 0, stream>>>(
        CONV2B, gn_g + 512, gn_b + 512, 512, (u16*)0, 0, GN2F);
    maeeg_transpose_pos_kernel<<<dim3(16, 32), 256, 0, stream>>>(GN2F, PET, C, Cb);

    // ---- transformer encoder ----
    for (int l = 0; l < 4; ++l) {
        maeeg_mm_kernel<<<dim3(128, 6), 256, 0, stream>>>(
            Cb, WQKVb + l * 196608, (const float*)0, (const float*)0,
            Qb2, 256, 256, 16);
        maeeg_fattn_kernel<<<dim3(4, 8, 32), 256, 0, stream>>>(
            Qb2, Qb2 + 4194304, Qb2 + 8388608, ATTb);
        // Wo + residual(C) + LN1 -> D (fp32) + Db (bf16)
        maeeg_mmln_kernel<<<256, 512, 0, stream>>>(
            ATTb, WOb + l * 65536, (const float*)0, C,
            ln1_g + l * 256, ln1_b + l * 256, D, Db, 256);
        maeeg_mm_kernel<<<dim3(128, 8), 256, 0, stream>>>(
            Db, WF1b + l * 262144, bf1 + l * 1024, (const float*)0, F1b, 1024, 256, 3);
        // FF2 + bias + residual(D) + LN2 -> C (fp32, skipped on last layer) + Cb
        maeeg_mmln_kernel<<<256, 512, 0, stream>>>(
            F1b, WF2b + l * 262144, bf2 + l * 256, D,
            ln2_g + l * 256, ln2_b + l * 256, (l == 3) ? (float*)0 : C, Cb, 1024);
    }

    // ---- classifier ----
    maeeg_cls1_kernel<<<dim3(128, 4), 256, 0, stream>>>(Cb, Wc1, PART);
    maeeg_cls23_kernel<<<32, 256, 0, stream>>>(PART, bc1, Wc2, bc2, out);
}

// Round 12
// 913.480 us; speedup vs baseline: 1.0595x; 1.0595x over previous
//
#include <hip/hip_runtime.h>
#include <math.h>

// ============================================================================
// MAEEG classification, round 12:
//   - fattn v3: round-10 v1 staging (single buffer -- the v2 prefetch caused
//     vmcnt(0) serialization); softmax in exp2 domain (log2e folded into the
//     Q projection scale -> raw v_exp_f32); P -> bf16 via round-half-up with
//     psum accumulated from the SAME rounded values (consistent softmax).
//   - cls1: split-K 256 (1024 blocks) for HBM latency hiding on Wc1; PART
//     relocated to the R2 region (dead at classifier time).
//   - everything else unchanged from round 11 (bf16 conv chain, GN-bf16,
//     mmln fusion, gl2lds GEMM staging).
// ============================================================================

typedef unsigned int   u32;
typedef unsigned short u16;
typedef __attribute__((ext_vector_type(4))) float f32x4;
typedef __attribute__((ext_vector_type(8))) short bf16x8;

// 1/sqrt(32) * log2(e): folds the softmax exp->exp2 conversion into Q scale
#define QSCALE_LOG2E 0.2550348742f

__device__ __forceinline__ u16 f2bf(float v) {
    union { float f; u32 u; } x; x.f = v;
    u32 r = x.u + 0x7fffu + ((x.u >> 16) & 1u);  // RNE
    return (u16)(r >> 16);
}

// async global->LDS DMA, 16B per lane; ldst must be wave-uniform
__device__ __forceinline__ void gl2lds16(const void* gsrc, void* ldst) {
    __builtin_amdgcn_global_load_lds(
        (const __attribute__((address_space(1))) void*)gsrc,
        (__attribute__((address_space(3))) void*)ldst, 16, 0, 0);
}

// ---------------------------------------------------------------------------
__device__ __forceinline__ float maeeg_block_sum(float v, float* sc4) {
#pragma unroll
    for (int off = 32; off; off >>= 1) v += __shfl_down(v, off);
    int t = threadIdx.x;
    if ((t & 63) == 0) sc4[t >> 6] = v;
    __syncthreads();
    float r = sc4[0] + sc4[1] + sc4[2] + sc4[3];
    __syncthreads();
    return r;
}

// ---------------------------------------------------------------------------
// bf16 MFMA GEMM: out[m][n] = sum_k A[m][k]*B[n][k] (+bias[n]) (+res)
// flags: 1 relu | 2 bf16 out | 4 transposed bf16 out | 16 fused-QKV routing
__global__ __launch_bounds__(256) void maeeg_mm_kernel(
    const u16* __restrict__ Ag, const u16* __restrict__ Bg,
    const float* __restrict__ bias, const float* __restrict__ res,
    void* __restrict__ outp, int N, int K, int flags)
{
    __shared__ u16 As[8192];  // [128 rows][64 k] bf16, 128B/row, XOR-swizzled
    __shared__ u16 Bs[8192];
    const int m0 = blockIdx.x * 128, n0 = blockIdx.y * 128;
    const int t = threadIdx.x, w = t >> 6, lane = t & 63;
    const int fr = lane & 15, fq = lane >> 4;
    const int wm = (w >> 1) * 64, wn = (w & 1) * 64;
    const int srow = lane >> 3;
    const int srcc = (lane & 7) ^ srow;

    f32x4 acc[4][4];
    const f32x4 zero = {0.f, 0.f, 0.f, 0.f};
#pragma unroll
    for (int i = 0; i < 4; ++i)
#pragma unroll
        for (int j = 0; j < 4; ++j) acc[i][j] = zero;

    for (int k0 = 0; k0 < K; k0 += 64) {
#pragma unroll
        for (int j = 0; j < 4; ++j) {
            int rowb = w * 32 + j * 8;
            int r = rowb + srow;
            gl2lds16(Ag + (size_t)(m0 + r) * K + k0 + srcc * 8,
                     (char*)As + rowb * 128);
            gl2lds16(Bg + (size_t)(n0 + r) * K + k0 + srcc * 8,
                     (char*)Bs + rowb * 128);
        }
        __syncthreads();
#pragma unroll
        for (int kc = 0; kc < 2; ++kc) {
            bf16x8 af[4], bfv[4];
#pragma unroll
            for (int i = 0; i < 4; ++i) {
                int am = wm + i * 16 + fr;
                int bn = wn + i * 16 + fr;
                int kb = kc * 64 + fq * 16;
                af[i]  = *(const bf16x8*)((const char*)As + am * 128 + (kb ^ ((am & 7) << 4)));
                bfv[i] = *(const bf16x8*)((const char*)Bs + bn * 128 + (kb ^ ((bn & 7) << 4)));
            }
#pragma unroll
            for (int i = 0; i < 4; ++i)
#pragma unroll
                for (int j = 0; j < 4; ++j)
                    acc[i][j] = __builtin_amdgcn_mfma_f32_16x16x32_bf16(
                        af[i], bfv[j], acc[i][j], 0, 0, 0);
        }
        __syncthreads();
    }
#pragma unroll
    for (int i = 0; i < 4; ++i) {
#pragma unroll
        for (int j = 0; j < 4; ++j) {
            int n = n0 + wn + j * 16 + fr;
            float bv = bias ? bias[n] : 0.f;
#pragma unroll
            for (int r = 0; r < 4; ++r) {
                int m = m0 + wm + i * 16 + fq * 4 + r;
                float v = acc[i][j][r] + bv;
                if (res) v += res[(size_t)m * N + n];
                if (flags & 1) v = fmaxf(v, 0.f);
                if (flags & 16) {
                    // fused QKV: seg0 -> Q (scaled into exp2 domain), seg1 -> K,
                    // seg2 -> V^T
                    u16* o = (u16*)outp;
                    int seg = n >> 8, nn = n & 255;
                    if (seg == 0)
                        o[(size_t)m * 256 + nn] = f2bf(v * QSCALE_LOG2E);
                    else if (seg == 1)
                        o[4194304 + (size_t)m * 256 + nn] = f2bf(v);
                    else
                        o[8388608 + (((size_t)(m >> 9)) * 256 + nn) * 512 + (m & 511)] = f2bf(v);
                } else if (flags & 4)
                    ((u16*)outp)[(((size_t)(m >> 9)) * 256 + n) * 512 + (m & 511)] = f2bf(v);
                else if (flags & 2)
                    ((u16*)outp)[(size_t)m * N + n] = f2bf(v);
                else
                    ((float*)outp)[(size_t)m * N + n] = v;
            }
        }
    }
}

// ---------------------------------------------------------------------------
// fused GEMM + residual + LayerNorm: out = LN(A@B^T + bias + res)*g + b
__global__ __launch_bounds__(512) void maeeg_mmln_kernel(
    const u16* __restrict__ Ag, const u16* __restrict__ Bg,
    const float* __restrict__ bias, const float* __restrict__ res,
    const float* __restrict__ g, const float* __restrict__ b,
    float* __restrict__ outf, u16* __restrict__ outb, int K)
{
    __shared__ u16 As[64 * 64];    // 8KB  [64 m][64 k], swizzled
    __shared__ u16 Bs[256 * 64];   // 32KB [256 n][64 k]
    __shared__ float psum[64][4];
    __shared__ float psq[64][4];
    const int m0 = blockIdx.x * 64;
    const int t = threadIdx.x, w = t >> 6, lane = t & 63;
    const int fr = lane & 15, fq = lane >> 4;
    const int wm = (w & 1) * 32, wn = (w >> 1) * 64;
    const int seg = w >> 1;
    const int srow = lane >> 3;
    const int srcc = (lane & 7) ^ srow;

    f32x4 acc[2][4];
    const f32x4 zero = {0.f, 0.f, 0.f, 0.f};
#pragma unroll
    for (int i = 0; i < 2; ++i)
#pragma unroll
        for (int j = 0; j < 4; ++j) acc[i][j] = zero;

    for (int k0 = 0; k0 < K; k0 += 64) {
        gl2lds16(Ag + (size_t)(m0 + w * 8 + srow) * K + k0 + srcc * 8,
                 (char*)As + (w * 8) * 128);
#pragma unroll
        for (int j = 0; j < 4; ++j) {
            int rowb = w * 32 + j * 8;
            gl2lds16(Bg + (size_t)(rowb + srow) * K + k0 + srcc * 8,
                     (char*)Bs + rowb * 128);
        }
        __syncthreads();
#pragma unroll
        for (int kc = 0; kc < 2; ++kc) {
            int kb = kc * 64 + fq * 16;
            bf16x8 af[2], bfv[4];
#pragma unroll
            for (int i = 0; i < 2; ++i) {
                int am = wm + i * 16 + fr;
                af[i] = *(const bf16x8*)((const char*)As + am * 128 + (kb ^ ((am & 7) << 4)));
            }
#pragma unroll
            for (int j = 0; j < 4; ++j) {
                int bn = wn + j * 16 + fr;
                bfv[j] = *(const bf16x8*)((const char*)Bs + bn * 128 + (kb ^ ((bn & 7) << 4)));
            }
#pragma unroll
            for (int i = 0; i < 2; ++i)
#pragma unroll
                for (int j = 0; j < 4; ++j)
                    acc[i][j] = __builtin_amdgcn_mfma_f32_16x16x32_bf16(
                        af[i], bfv[j], acc[i][j], 0, 0, 0);
        }
        __syncthreads();
    }

#pragma unroll
    for (int j = 0; j < 4; ++j) {
        int n = wn + j * 16 + fr;
        float bv = bias ? bias[n] : 0.f;
#pragma unroll
        for (int i = 0; i < 2; ++i)
#pragma unroll
            for (int r = 0; r < 4; ++r) {
                int m = m0 + wm + i * 16 + fq * 4 + r;
                acc[i][j][r] += bv + res[(size_t)m * 256 + n];
            }
    }
#pragma unroll
    for (int i = 0; i < 2; ++i)
#pragma unroll
        for (int r = 0; r < 4; ++r) {
            float s = acc[i][0][r] + acc[i][1][r] + acc[i][2][r] + acc[i][3][r];
            float q = acc[i][0][r] * acc[i][0][r] + acc[i][1][r] * acc[i][1][r]
                    + acc[i][2][r] * acc[i][2][r] + acc[i][3][r] * acc[i][3][r];
#pragma unroll
            for (int off = 1; off < 16; off <<= 1) {
                s += __shfl_xor(s, off);
                q += __shfl_xor(q, off);
            }
            if (fr == 0) {
                int ml = wm + i * 16 + fq * 4 + r;
                psum[ml][seg] = s;
                psq[ml][seg] = q;
            }
        }
    __syncthreads();
#pragma unroll
    for (int i = 0; i < 2; ++i)
#pragma unroll
        for (int r = 0; r < 4; ++r) {
            int ml = wm + i * 16 + fq * 4 + r;
            float S = psum[ml][0] + psum[ml][1] + psum[ml][2] + psum[ml][3];
            float Q = psq[ml][0] + psq[ml][1] + psq[ml][2] + psq[ml][3];
            float mu = S * (1.f / 256.f);
            float var = fmaxf(Q * (1.f / 256.f) - mu * mu, 0.f);
            float rs = rsqrtf(var + 1e-5f);
            size_t mrow = (size_t)(m0 + ml) * 256;
#pragma unroll
            for (int j = 0; j < 4; ++j) {
                int n = wn + j * 16 + fr;
                float o = (acc[i][j][r] - mu) * rs * g[n] + b[n];
                if (outf) outf[mrow + n] = o;
                outb[mrow + n] = f2bf(o);
            }
        }
}

// ---------------------------------------------------------------------------
// bf16 MFMA implicit-GEMM conv1d (stride 2, taps 15 padded to 16). bf16 out.
__global__ __launch_bounds__(256) void maeeg_convmm_kernel(
    const u16* __restrict__ Wp, const u16* __restrict__ inp,
    const float* __restrict__ cb, u16* __restrict__ out,
    int K3, int len_in, int len_out)
{
    __shared__ u16 As[8192];
    __shared__ u16 Bs[8192];
    const int m0 = blockIdx.x * 128, t0 = blockIdx.y * 128, b = blockIdx.z;
    const int lip = len_in + 16;
    const u16* inb = inp + (size_t)b * (K3 >> 4) * lip;
    const int t = threadIdx.x, w = t >> 6, lane = t & 63;
    const int sr = lane & 7, sc = lane >> 3;
    const int fr = lane & 15, fq = lane >> 4;
    const int wm = (w >> 1) * 64, wn = (w & 1) * 64;
    const int srow = lane >> 3;
    const int srcc = (lane & 7) ^ srow;

    f32x4 acc[4][4];
    const f32x4 zero = {0.f, 0.f, 0.f, 0.f};
#pragma unroll
    for (int i = 0; i < 4; ++i)
#pragma unroll
        for (int j = 0; j < 4; ++j) acc[i][j] = zero;

    for (int k0 = 0; k0 < K3; k0 += 64) {
#pragma unroll
        for (int j = 0; j < 4; ++j) {
            int rowb = w * 32 + j * 8;
            gl2lds16(Wp + (size_t)(m0 + rowb + srow) * K3 + k0 + srcc * 8,
                     (char*)As + rowb * 128);
            int row = rowb + sr;
            int k  = k0 + sc * 8;
            int ci = k >> 4, rr = k & 15;
            int tg = t0 + row;
            const u16* gp = inb + (size_t)ci * lip + 2 * tg + rr;
            uint4 vb;
            vb.x = *(const u32*)(gp);
            vb.y = *(const u32*)(gp + 2);
            vb.z = *(const u32*)(gp + 4);
            vb.w = *(const u32*)(gp + 6);
            int kb = (sc ^ (row & 7)) << 4;
            *(uint4*)((char*)Bs + row * 128 + kb) = vb;
        }
        __syncthreads();
#pragma unroll
        for (int kc = 0; kc < 2; ++kc) {
            bf16x8 af[4], bfv[4];
#pragma unroll
            for (int i = 0; i < 4; ++i) {
                int am = wm + i * 16 + fr;
                int bn = wn + i * 16 + fr;
                int kb = kc * 64 + fq * 16;
                af[i]  = *(const bf16x8*)((const char*)As + am * 128 + (kb ^ ((am & 7) << 4)));
                bfv[i] = *(const bf16x8*)((const char*)Bs + bn * 128 + (kb ^ ((bn & 7) << 4)));
            }
#pragma unroll
            for (int i = 0; i < 4; ++i)
#pragma unroll
                for (int j = 0; j < 4; ++j)
                    acc[i][j] = __builtin_amdgcn_mfma_f32_16x16x32_bf16(
                        af[i], bfv[j], acc[i][j], 0, 0, 0);
        }
        __syncthreads();
    }
#pragma unroll
    for (int i = 0; i < 4; ++i) {
#pragma unroll
        for (int r = 0; r < 4; ++r) {
            int m = m0 + wm + i * 16 + fq * 4 + r;
            float bb = cb[m];
            u16* op = out + ((size_t)b * 256 + m) * len_out + t0;
#pragma unroll
            for (int j = 0; j < 4; ++j)
                op[wn + j * 16 + fr] = f2bf(acc[i][j][r] + bb);
        }
    }
}

// ---------------------------------------------------------------------------
// MFMA flash attention v3: v1 single-buffer staging; softmax in exp2 domain
// (Q pre-scaled by log2e/sqrt(32)); P rounded half-up with psum accumulated
// from the SAME rounded values (consistent softmax). grid (4,8,32), 256 thr.
__global__ __launch_bounds__(256) void maeeg_fattn_kernel(
    const u16* __restrict__ Qb, const u16* __restrict__ Kb,
    const u16* __restrict__ Vt, u16* __restrict__ att)
{
    __shared__ u16 Ks[64 * 32];      // [64 kk][32 d], 64B rows, chunk^=(kk&3)
    __shared__ u16 Vs[32 * 64];      // [32 d][64 kk], 128B rows, chunk^=(d&7)
    __shared__ u16 Ps[4][32 * 64];   // per-wave [32 q][64 kk], chunk^=(q&7)
    const int qt = blockIdx.x, h = blockIdx.y, b = blockIdx.z;
    const int t = threadIdx.x, w = t >> 6, lane = t & 63;
    const int fr = lane & 15, fq = lane >> 4;
    const u16* qbase = Qb + (size_t)b * 512 * 256 + h * 32;
    const u16* kbase = Kb + (size_t)b * 512 * 256 + h * 32;
    const u16* vbase = Vt + (size_t)b * 256 * 512 + (size_t)h * 32 * 512;

    bf16x8 qf[2];
#pragma unroll
    for (int mi = 0; mi < 2; ++mi)
        qf[mi] = *(const bf16x8*)(qbase +
                 (size_t)(qt * 128 + w * 32 + mi * 16 + fr) * 256 + fq * 8);

    f32x4 oacc[2][2];
    const f32x4 zero = {0.f, 0.f, 0.f, 0.f};
    oacc[0][0] = zero; oacc[0][1] = zero; oacc[1][0] = zero; oacc[1][1] = zero;
    float mrun[8], lrun[8];
#pragma unroll
    for (int i = 0; i < 8; ++i) { mrun[i] = -1e30f; lrun[i] = 0.f; }

    for (int kt = 0; kt < 512; kt += 64) {
        {   // stage K tile (4KB) + Vt tile (4KB), swizzled
            int row = t >> 2, c = t & 3;
            uint4 kv = *(const uint4*)(kbase + (size_t)(kt + row) * 256 + c * 8);
            *(uint4*)((char*)Ks + row * 64 + (((c ^ (row & 3)) << 4))) = kv;
            int d = t >> 3, c2 = t & 7;
            uint4 vv = *(const uint4*)(vbase + (size_t)d * 512 + kt + c2 * 8);
            *(uint4*)((char*)Vs + d * 128 + ((c2 ^ (d & 7)) << 4)) = vv;
        }
        __syncthreads();

        // ---- QK^T (scores already in exp2 domain): S[32 q][64 kk] ----
        f32x4 sacc[2][4];
#pragma unroll
        for (int mi = 0; mi < 2; ++mi)
#pragma unroll
            for (int ni = 0; ni < 4; ++ni) sacc[mi][ni] = zero;
        bf16x8 kf[4];
#pragma unroll
        for (int ni = 0; ni < 4; ++ni) {
            int kk = ni * 16 + fr;
            kf[ni] = *(const bf16x8*)((const char*)Ks + kk * 64 +
                                      ((fq ^ (kk & 3)) << 4));
        }
#pragma unroll
        for (int mi = 0; mi < 2; ++mi)
#pragma unroll
            for (int ni = 0; ni < 4; ++ni)
                sacc[mi][ni] = __builtin_amdgcn_mfma_f32_16x16x32_bf16(
                    qf[mi], kf[ni], sacc[mi][ni], 0, 0, 0);

        // ---- online softmax (exp2 domain, rows = fq*4+reg per 16-block) ----
#pragma unroll
        for (int mi = 0; mi < 2; ++mi) {
#pragma unroll
            for (int reg = 0; reg < 4; ++reg) {
                int idx = mi * 4 + reg;
                float rm = fmaxf(fmaxf(sacc[mi][0][reg], sacc[mi][1][reg]),
                                 fmaxf(sacc[mi][2][reg], sacc[mi][3][reg]));
                rm = fmaxf(rm, __shfl_xor(rm, 1));
                rm = fmaxf(rm, __shfl_xor(rm, 2));
                rm = fmaxf(rm, __shfl_xor(rm, 4));
                rm = fmaxf(rm, __shfl_xor(rm, 8));
                float mold = mrun[idx];
                float mnew = fmaxf(mold, rm);
                float c = __builtin_amdgcn_exp2f(mold - mnew);
                mrun[idx] = mnew;
                int q = mi * 16 + fq * 4 + reg;
                float psum = 0.f;
#pragma unroll
                for (int ni = 0; ni < 4; ++ni) {
                    float p = __builtin_amdgcn_exp2f(sacc[mi][ni][reg] - mnew);
                    union { float f; u32 u; } px; px.f = p;
                    u32 r16 = (px.u + 0x8000u) >> 16;   // round-half-up bf16
                    int kk = ni * 16 + fr;
                    int boff = q * 128 + ((((kk >> 3) ^ (q & 7)) << 4) | ((kk & 7) << 1));
                    *(u16*)((char*)Ps[w] + boff) = (u16)r16;
                    union { u32 u; float f; } pr; pr.u = r16 << 16;
                    psum += pr.f;                        // consistent with stored P
                }
                lrun[idx] = lrun[idx] * c + psum;
                oacc[mi][0][reg] *= c;
                oacc[mi][1][reg] *= c;
            }
        }

        // ---- PV: O[32 q][32 d] += P @ V ----
        bf16x8 pf[2][2], vf[2][2];
#pragma unroll
        for (int mi = 0; mi < 2; ++mi)
#pragma unroll
            for (int kc = 0; kc < 2; ++kc) {
                int q = mi * 16 + fr;
                int ch = (kc * 4 + fq) ^ (q & 7);
                pf[mi][kc] = *(const bf16x8*)((const char*)Ps[w] + q * 128 + (ch << 4));
            }
#pragma unroll
        for (int nj = 0; nj < 2; ++nj)
#pragma unroll
            for (int kc = 0; kc < 2; ++kc) {
                int d = nj * 16 + fr;
                int ch = (kc * 4 + fq) ^ (d & 7);
                vf[nj][kc] = *(const bf16x8*)((const char*)Vs + d * 128 + (ch << 4));
            }
#pragma unroll
        for (int mi = 0; mi < 2; ++mi)
#pragma unroll
            for (int nj = 0; nj < 2; ++nj) {
                oacc[mi][nj] = __builtin_amdgcn_mfma_f32_16x16x32_bf16(
                    pf[mi][0], vf[nj][0], oacc[mi][nj], 0, 0, 0);
                oacc[mi][nj] = __builtin_amdgcn_mfma_f32_16x16x32_bf16(
                    pf[mi][1], vf[nj][1], oacc[mi][nj], 0, 0, 0);
            }
        __syncthreads();
    }

#pragma unroll
    for (int idx = 0; idx < 8; ++idx) {
        float l = lrun[idx];
        l += __shfl_xor(l, 1);
        l += __shfl_xor(l, 2);
        l += __shfl_xor(l, 4);
        l += __shfl_xor(l, 8);
        lrun[idx] = 1.f / l;
    }
    u16* ob = att + (size_t)b * 512 * 256 + h * 32;
#pragma unroll
    for (int mi = 0; mi < 2; ++mi)
#pragma unroll
        for (int reg = 0; reg < 4; ++reg) {
            int q = qt * 128 + w * 32 + mi * 16 + fq * 4 + reg;
            float inv = lrun[mi * 4 + reg];
#pragma unroll
            for (int nj = 0; nj < 2; ++nj)
                ob[(size_t)q * 256 + nj * 16 + fr] =
                    f2bf(oacc[mi][nj][reg] * inv);
        }
}

// ---------------------------------------------------------------------------
// weight prep: one thread per 16-elem output row (15 taps + zero pad)
__global__ void maeeg_prep_convw_kernel(const float* __restrict__ src,
                                        u16* __restrict__ dst, int nrows)
{
    int i = blockIdx.x * 256 + threadIdx.x;
    if (i >= nrows) return;
    const float* s = src + (size_t)i * 15;
    float4 a = *(const float4*)s;
    float4 b = *(const float4*)(s + 4);
    float4 c = *(const float4*)(s + 8);
    float e12 = s[12], e13 = s[13], e14 = s[14];
    uint4 p0, p1;
    p0.x = (u32)f2bf(a.x) | ((u32)f2bf(a.y) << 16);
    p0.y = (u32)f2bf(a.z) | ((u32)f2bf(a.w) << 16);
    p0.z = (u32)f2bf(b.x) | ((u32)f2bf(b.y) << 16);
    p0.w = (u32)f2bf(b.z) | ((u32)f2bf(b.w) << 16);
    p1.x = (u32)f2bf(c.x) | ((u32)f2bf(c.y) << 16);
    p1.y = (u32)f2bf(c.z) | ((u32)f2bf(c.w) << 16);
    p1.z = (u32)f2bf(e12) | ((u32)f2bf(e13) << 16);
    p1.w = (u32)f2bf(e14);
    uint4* d = (uint4*)(dst + (size_t)i * 16);
    d[0] = p0; d[1] = p1;
}

__device__ __forceinline__ uint4 pack8(const float* s) {
    float4 a = ((const float4*)s)[0];
    float4 b = ((const float4*)s)[1];
    uint4 p;
    p.x = (u32)f2bf(a.x) | ((u32)f2bf(a.y) << 16);
    p.y = (u32)f2bf(a.z) | ((u32)f2bf(a.w) << 16);
    p.z = (u32)f2bf(b.x) | ((u32)f2bf(b.y) << 16);
    p.w = (u32)f2bf(b.z) | ((u32)f2bf(b.w) << 16);
    return p;
}

// merged cast for Wo (32768 x8) + Wf1 (131072 x8) + Wf2 (131072 x8)
__global__ void maeeg_cast_www_kernel(
    const float* __restrict__ Wo, u16* __restrict__ dWo,
    const float* __restrict__ Wf1, u16* __restrict__ dWf1,
    const float* __restrict__ Wf2, u16* __restrict__ dWf2)
{
    int i = blockIdx.x * 256 + threadIdx.x;
    const float* s; u16* d; int off;
    if (i < 32768)       { s = Wo;  d = dWo;  off = i; }
    else if (i < 163840) { s = Wf1; d = dWf1; off = i - 32768; }
    else                 { s = Wf2; d = dWf2; off = i - 163840; }
    *(uint4*)(d + (size_t)off * 8) = pack8(s + (size_t)off * 8);
}

// merged QKV pack: [L][65536] x3 -> WQKV [L][3][65536], grid (128, 3)
__global__ void maeeg_cast_qkv3_kernel(
    const float* __restrict__ Wq, const float* __restrict__ Wk,
    const float* __restrict__ Wv, u16* __restrict__ dst)
{
    int seg = blockIdx.y;
    const float* src = (seg == 0) ? Wq : ((seg == 1) ? Wk : Wv);
    int i = blockIdx.x * 256 + threadIdx.x;  // 0..32767
    int l = i >> 13, r = (i & 8191) * 8;
    *(uint4*)(dst + (size_t)l * 196608 + seg * 65536 + r) =
        pack8(src + (size_t)i * 8);
}

// fp32 [rows][len] -> bf16 [rows][len+16], 7 leading zeros; 8 outs/thread
__global__ void maeeg_cast_pad_kernel(const float* __restrict__ src,
                                      u16* __restrict__ dst, int len)
{
    int lip = len + 16;
    int n8 = lip >> 3;
    int i = blockIdx.x * 256 + threadIdx.x;
    if (i >= n8) return;
    int row = blockIdx.y;
    int p0 = i * 8;
    u16 vals[8];
#pragma unroll
    for (int e = 0; e < 8; ++e) {
        int q = p0 + e - 7;
        vals[e] = (q >= 0 && q < len) ? f2bf(src[(size_t)row * len + q]) : (u16)0;
    }
    uint4 pk;
    pk.x = (u32)vals[0] | ((u32)vals[1] << 16);
    pk.y = (u32)vals[2] | ((u32)vals[3] << 16);
    pk.z = (u32)vals[4] | ((u32)vals[5] << 16);
    pk.w = (u32)vals[6] | ((u32)vals[7] << 16);
    *(uint4*)(dst + (size_t)row * lip + p0) = pk;
}

// sinusoidal PE table [512][256]
__global__ void maeeg_pe_kernel(float* __restrict__ pet)
{
    int s = blockIdx.x, e = threadIdx.x;
    float ang = (float)s / powf(10000.f, (float)e * (1.f / 256.f));
    pet[s * 256 + e] = (e & 1) ? cosf(ang) : sinf(ang);
}

// ---------------------------------------------------------------------------
// GroupNorm (2 ch/group) + exact GELU over bf16 input. Writes padded bf16
// shadow (bfout, nullable) and/or fp32 (f32out, nullable).
__global__ __launch_bounds__(256) void maeeg_gn_gelu_kernel(
    const u16* __restrict__ hin, const float* __restrict__ g,
    const float* __restrict__ bta, int len, u16* __restrict__ bfout, int lip,
    float* __restrict__ f32out)
{
    const int grp = blockIdx.x, b = blockIdx.y;
    const size_t base = ((size_t)b * 256 + grp * 2) * len;
    const u32* p32 = (const u32*)(hin + base);
    float s1 = 0.f, s2 = 0.f;
    for (int i = threadIdx.x; i < len; i += 256) {  // len u32s = 2*len bf16
        u32 v = p32[i];
        union { u32 u; float f; } lo, hi;
        lo.u = v << 16; hi.u = v & 0xffff0000u;
        s1 += lo.f + hi.f;
        s2 += lo.f * lo.f + hi.f * hi.f;
    }
    __shared__ float sc[4];
    float S1 = maeeg_block_sum(s1, sc);
    float S2 = maeeg_block_sum(s2, sc);
    const float nn = (float)(2 * len);
    float mu = S1 / nn;
    float var = fmaxf(S2 / nn - mu * mu, 0.f);
    float rs = rsqrtf(var + 1e-5f);
    float g0 = g[grp * 2], g1 = g[grp * 2 + 1];
    float b0 = bta[grp * 2], b1 = bta[grp * 2 + 1];
    u16* bp = bfout ? bfout + ((size_t)b * 256 + grp * 2) * lip : (u16*)0;
    float* fp = f32out ? f32out + base : (float*)0;
    for (int i2 = threadIdx.x; i2 < len; i2 += 256) {
        u32 v = p32[i2];
        int i = i2 * 2;
        union { u32 u; float f; } lo, hi;
        lo.u = v << 16; hi.u = v & 0xffff0000u;
        bool c1 = (i >= len);
        float gg = c1 ? g1 : g0, bb = c1 ? b1 : b0;
        float y0 = (lo.f - mu) * rs * gg + bb;
        float y1 = (hi.f - mu) * rs * gg + bb;
        float e0 = 0.5f * y0 * (1.f + erff(y0 * 0.70710678118654752f));
        float e1 = 0.5f * y1 * (1.f + erff(y1 * 0.70710678118654752f));
        if (bp) {
            int j0 = (i < len ? i : i - len + lip) + 7;
            bp[j0] = f2bf(e0);
            bp[j0 + 1] = f2bf(e1);
        }
        if (fp) {
            fp[i] = e0;
            fp[i + 1] = e1;
        }
    }
    if (bp && threadIdx.x < 32) {  // zero the pads (ws is 0xAA-poisoned)
        int ch = threadIdx.x >> 4, pp = threadIdx.x & 15;
        bp[(size_t)ch * lip + ((pp < 7) ? pp : (len + pp))] = 0;
    }
}

// ---------------------------------------------------------------------------
// transpose [B,256,512] -> [B,512,256], add PE from table; fp32 + bf16.
__global__ __launch_bounds__(256) void maeeg_transpose_pos_kernel(
    const float* __restrict__ in, const float* __restrict__ pet,
    float* __restrict__ out, u16* __restrict__ outb)
{
    __shared__ float tile[256][33];
    const int s0 = blockIdx.x * 32, b = blockIdx.y;
    for (int idx = threadIdx.x; idx < 256 * 32; idx += 256) {
        int e = idx >> 5, j = idx & 31;
        tile[e][j] = in[((size_t)b * 256 + e) * 512 + s0 + j];
    }
    __syncthreads();
    for (int idx = threadIdx.x; idx < 32 * 256; idx += 256) {
        int j = idx >> 8, e = idx & 255;
        float v = tile[e][j] + pet[(s0 + j) * 256 + e];
        size_t o = ((size_t)b * 512 + s0 + j) * 256 + e;
        out[o] = v;
        outb[o] = f2bf(v);
    }
}

// ---------------------------------------------------------------------------
// classifier stage 1: MFMA split-K (256 splits); A via global_load_lds,
// Wc1 fp32->bf16 inline (reg-staged). grid (256 ks, 4 jt), 256 thr.
__global__ __launch_bounds__(256) void maeeg_cls1_kernel(
    const u16* __restrict__ flatb, const float* __restrict__ Wc1,
    float* __restrict__ part)
{
    __shared__ u16 As[32 * 64];
    __shared__ u16 Bs[64 * 64];
    const int ks = blockIdx.x, jt = blockIdx.y;
    const int t = threadIdx.x, w = t >> 6, lane = t & 63;
    const int fr = lane & 15, fq = lane >> 4;
    const int kbase0 = ks * 512;
    const int brow = t >> 2, bq = t & 3;
    const int srow = lane >> 3;
    const int srcc = (lane & 7) ^ srow;

    f32x4 acc[2];
    const f32x4 zero = {0.f, 0.f, 0.f, 0.f};
    acc[0] = zero; acc[1] = zero;

    for (int step = 0; step < 8; ++step) {
        int kk = kbase0 + step * 64;
        int rowb = w * 8;
        gl2lds16(flatb + (size_t)(rowb + srow) * 131072 + kk + srcc * 8,
                 (char*)As + rowb * 128);
        const float* wp = Wc1 + (size_t)(jt * 64 + brow) * 131072 + kk + bq * 16;
        float4 f0 = ((const float4*)wp)[0];
        float4 f1 = ((const float4*)wp)[1];
        float4 f2 = ((const float4*)wp)[2];
        float4 f3 = ((const float4*)wp)[3];
        uint4 p0, p1;
        p0.x = (u32)f2bf(f0.x) | ((u32)f2bf(f0.y) << 16);
        p0.y = (u32)f2bf(f0.z) | ((u32)f2bf(f0.w) << 16);
        p0.z = (u32)f2bf(f1.x) | ((u32)f2bf(f1.y) << 16);
        p0.w = (u32)f2bf(f1.z) | ((u32)f2bf(f1.w) << 16);
        p1.x = (u32)f2bf(f2.x) | ((u32)f2bf(f2.y) << 16);
        p1.y = (u32)f2bf(f2.z) | ((u32)f2bf(f2.w) << 16);
        p1.z = (u32)f2bf(f3.x) | ((u32)f2bf(f3.y) << 16);
        p1.w = (u32)f2bf(f3.z) | ((u32)f2bf(f3.w) << 16);
        int c0 = bq * 2, c1 = bq * 2 + 1;
        *(uint4*)((char*)Bs + brow * 128 + ((c0 ^ (brow & 7)) << 4)) = p0;
        *(uint4*)((char*)Bs + brow * 128 + ((c1 ^ (brow & 7)) << 4)) = p1;
        __syncthreads();
#pragma unroll
        for (int kc = 0; kc < 2; ++kc) {
            int kbyte = kc * 64 + fq * 16;
            int bn = w * 16 + fr;
            bf16x8 bfv = *(const bf16x8*)((const char*)Bs + bn * 128 +
                                          (kbyte ^ ((bn & 7) << 4)));
#pragma unroll
            for (int mi = 0; mi < 2; ++mi) {
                int am = mi * 16 + fr;
                bf16x8 af = *(const bf16x8*)((const char*)As + am * 128 +
                                             (kbyte ^ ((am & 7) << 4)));
                acc[mi] = __builtin_amdgcn_mfma_f32_16x16x32_bf16(
                    af, bfv, acc[mi], 0, 0, 0);
            }
        }
        __syncthreads();
    }
#pragma unroll
    for (int mi = 0; mi < 2; ++mi)
#pragma unroll
        for (int r = 0; r < 4; ++r) {
            int m = mi * 16 + fq * 4 + r;
            int j = jt * 64 + w * 16 + fr;
            part[((size_t)ks * 32 + m) * 256 + j] = acc[mi][r];
        }
}

// fused cls2 (reduce+bias+relu) + cls3 (dot + sigmoid)
__global__ __launch_bounds__(256) void maeeg_cls23_kernel(
    const float* __restrict__ part, const float* __restrict__ bc1,
    const float* __restrict__ Wc2, const float* __restrict__ bc2,
    float* __restrict__ out)
{
    const int b = blockIdx.x, j = threadIdx.x;
    float s = bc1[j];
    for (int ks = 0; ks < 256; ++ks) s += part[((size_t)ks * 32 + b) * 256 + j];
    float v = fmaxf(s, 0.f) * Wc2[j];
    __shared__ float sc[4];
    float tot = maeeg_block_sum(v, sc);
    if (j == 0) out[b] = 1.f / (1.f + expf(-(tot + bc2[0])));
}

// ===========================================================================
extern "C" void kernel_launch(void* const* d_in, const int* in_sizes, int n_in,
                              void* d_out, int out_size, void* d_ws, size_t ws_size,
                              hipStream_t stream)
{
    (void)in_sizes; (void)n_in; (void)out_size; (void)ws_size;
    const float* x        = (const float*)d_in[0];
    const float* conv0_w  = (const float*)d_in[1];
    const float* conv0_b  = (const float*)d_in[2];
    const float* conv12_w = (const float*)d_in[3];
    const float* conv12_b = (const float*)d_in[4];
    const float* gn_g     = (const float*)d_in[5];
    const float* gn_b     = (const float*)d_in[6];
    const float* Wq       = (const float*)d_in[7];
    const float* Wk       = (const float*)d_in[8];
    const float* Wv       = (const float*)d_in[9];
    const float* Wo       = (const float*)d_in[10];
    const float* ln1_g    = (const float*)d_in[11];
    const float* ln1_b    = (const float*)d_in[12];
    const float* Wf1      = (const float*)d_in[13];
    const float* bf1      = (const float*)d_in[14];
    const float* Wf2      = (const float*)d_in[15];
    const float* bf2      = (const float*)d_in[16];
    const float* ln2_g    = (const float*)d_in[17];
    const float* ln2_b    = (const float*)d_in[18];
    const float* Wc1      = (const float*)d_in[19];
    const float* bc1      = (const float*)d_in[20];
    const float* Wc2      = (const float*)d_in[21];
    const float* bc2      = (const float*)d_in[22];
    float* out = (float*)d_out;

    // ---- workspace layout (bytes) ----
    char* wsb = (char*)d_ws;
    u16* WB0   = (u16*)(wsb + 0);          //   524,288
    u16* WB12  = (u16*)(wsb + 524288);     // 4,194,304
    u16* WQKVb = (u16*)(wsb + 4718592);    // 1,572,864 [L][3][256][256]
    u16* WOb   = (u16*)(wsb + 6291456);    //   524,288
    u16* WF1b  = (u16*)(wsb + 6815744);    // 2,097,152
    u16* WF2b  = (u16*)(wsb + 8912896);    // 2,097,152 -> 11,010,048
    // R1: XPAD -> GN1B -> D
    u16*   XPAD  = (u16*)(wsb + 11010048);
    u16*   GN1B  = (u16*)(wsb + 11010048);
    float* D     = (float*)(wsb + 11010048);
    // R2 (67,108,864): CONV0B -> CONV1B -> CONV2B/GN2F -> QKV/ATT/Db -> F1b
    //                  -> PART (classifier time; R2 dead by then)
    u16*   CONV0B = (u16*)(wsb + 28049408);              // 33.5 MB
    u16*   CONV1B = (u16*)(wsb + 28049408);              // 16.8 MB (conv0 dead)
    u16*   CONV2B = (u16*)(wsb + 28049408 + 33554432);   //  8.4 MB
    float* GN2F   = (float*)(wsb + 28049408);            // 16.8 MB (conv1 dead)
    u16*   Qb2   = (u16*)(wsb + 28049408);               // QKV packed base
    u16*   ATTb  = (u16*)(wsb + 28049408 + 25165824);
    u16*   Db    = (u16*)(wsb + 28049408 + 33554432);
    u16*   F1b   = (u16*)(wsb + 28049408);
    float* PART  = (float*)(wsb + 28049408);             // 8,388,608 (cls time)
    // R3: GN0B -> C + Cb
    u16*   GN0B  = (u16*)(wsb + 95158272);
    float* C     = (float*)(wsb + 95158272);
    u16*   Cb    = (u16*)(wsb + 95158272 + 16777216);    // == flat bf16
    // R4
    float* PET   = (float*)(wsb + 133201920);            //   524,288

    // ---- weight prep ----
    maeeg_prep_convw_kernel<<<64, 256, 0, stream>>>(conv0_w, WB0, 16384);
    maeeg_prep_convw_kernel<<<512, 256, 0, stream>>>(conv12_w, WB12, 131072);
    maeeg_cast_qkv3_kernel<<<dim3(128, 3), 256, 0, stream>>>(Wq, Wk, Wv, WQKVb);
    maeeg_cast_www_kernel<<<1152, 256, 0, stream>>>(Wo, WOb, Wf1, WF1b, Wf2, WF2b);
    maeeg_cast_pad_kernel<<<dim3(3, 2048), 256, 0, stream>>>(x, XPAD, 4096);
    maeeg_pe_kernel<<<512, 256, 0, stream>>>(PET);

    // ---- conv encoder (bf16 chain) ----
    maeeg_convmm_kernel<<<dim3(2, 16, 32), 256, 0, stream>>>(
        WB0, XPAD, conv0_b, CONV0B, 1024, 4096, 2048);
    maeeg_gn_gelu_kernel<<<dim3(128, 32), 256, 0, stream>>>(
        CONV0B, gn_g, gn_b, 2048, GN0B, 2064, (float*)0);
    maeeg_convmm_kernel<<<dim3(2, 8, 32), 256, 0, stream>>>(
        WB12, GN0B, conv12_b, CONV1B, 4096, 2048, 1024);
    maeeg_gn_gelu_kernel<<<dim3(128, 32), 256, 0, stream>>>(
        CONV1B, gn_g + 256, gn_b + 256, 1024, GN1B, 1040, (float*)0);
    maeeg_convmm_kernel<<<dim3(2, 4, 32), 256, 0, stream>>>(
        WB12 + 256 * 4096, GN1B, conv12_b + 256, CONV2B, 4096, 1024, 512);
    maeeg_gn_gelu_kernel<<<dim3(128, 32), 256, 0, stream>>>(
        CONV2B, gn_g + 512, gn_b + 512, 512, (u16*)0, 0, GN2F);
    maeeg_transpose_pos_kernel<<<dim3(16, 32), 256, 0, stream>>>(GN2F, PET, C, Cb);

    // ---- transformer encoder ----
    for (int l = 0; l < 4; ++l) {
        maeeg_mm_kernel<<<dim3(128, 6), 256, 0, stream>>>(
            Cb, WQKVb + l * 196608, (const float*)0, (const float*)0,
            Qb2, 256, 256, 16);
        maeeg_fattn_kernel<<<dim3(4, 8, 32), 256, 0, stream>>>(
            Qb2, Qb2 + 4194304, Qb2 + 8388608, ATTb);
        // Wo + residual(C) + LN1 -> D (fp32) + Db (bf16)
        maeeg_mmln_kernel<<<256, 512, 0, stream>>>(
            ATTb, WOb + l * 65536, (const float*)0, C,
            ln1_g + l * 256, ln1_b + l * 256, D, Db, 256);
        maeeg_mm_kernel<<<dim3(128, 8), 256, 0, stream>>>(
            Db, WF1b + l * 262144, bf1 + l * 1024, (const float*)0, F1b, 1024, 256, 3);
        // FF2 + bias + residual(D) + LN2 -> C (fp32, skipped on last layer) + Cb
        maeeg_mmln_kernel<<<256, 512, 0, stream>>>(
            F1b, WF2b + l * 262144, bf2 + l * 256, D,
            ln2_g + l * 256, ln2_b + l * 256, (l == 3) ? (float*)0 : C, Cb, 1024);
    }

    // ---- classifier ----
    maeeg_cls1_kernel<<<dim3(256, 4), 256, 0, stream>>>(Cb, Wc1, PART);
    maeeg_cls23_kernel<<<32, 256, 0, stream>>>(PART, bc1, Wc2, bc2, out);
}